// Round 9
// baseline (254.494 us; speedup 1.0000x reference)
//
#include <hip/hip_runtime.h>
#include <hip/hip_bf16.h>

#define D   128
#define GRP 32   // blocks per reduction group

// ---------------------------------------------------------------------------
// alpha_j = exp(c + b_w.X[j]); c cancels in the normalization, so only
// b_w = b_alpha^T W_alpha is needed.
//
// Structure (2 dispatches):
//  prep: b_w (1 block) + zero the ticket counters.
//  main: stream X once (R5 loop, measured ~15 us = 7.0 TB/s, L3-resident);
//        tail folded in via threadfence + atomic tickets:
//          - every block stores partials, takes a group ticket
//          - ticket GRP-1 block reduces its group's 32 partial rows
//          - group-last blocks take a global ticket; the last one does the
//            final 64-row reduce + normalize + W_sum matvec.
//        All reduction orders are fixed -> bit-identical across replays.
//        Cross-XCD partial reads use AGENT-scope atomic loads (stale-L2 safe).
// ---------------------------------------------------------------------------

// Kernel 1 (1 block, 1024 threads): b_w = b_alpha^T @ W_alpha; zero counters.
__global__ __launch_bounds__(1024) void prep_kernel(
    const float* __restrict__ W_alpha,
    const float* __restrict__ b_alpha,
    float* __restrict__ bw_out,   // [D]
    int* __restrict__ gcnt,       // [ngrp+1]
    int ngrp)
{
    const int t = threadIdx.x;
    for (int i = t; i <= ngrp; i += 1024) gcnt[i] = 0;

    const int k = t & 127;        // output column
    const int g = t >> 7;         // 0..7: 16 i-terms each
    __shared__ float bal[D];
    if (t < D) bal[t] = b_alpha[t];
    __syncthreads();

    float bw = 0.f;
    #pragma unroll
    for (int i = g * 16; i < g * 16 + 16; ++i)
        bw = fmaf(bal[i], W_alpha[i * D + k], bw);   // coalesced across k

    __shared__ float rbw[8][D];
    rbw[g][k] = bw;
    __syncthreads();
    if (t < D) {
        float B = 0.f;
        #pragma unroll
        for (int r = 0; r < 8; ++r) B += rbw[r][t];
        bw_out[t] = B;
    }
}

// ---------------------------------------------------------------------------
__global__ __launch_bounds__(256, 8) void main_pass_kernel(
    const float* __restrict__ X,
    const float* __restrict__ bw,
    const float* __restrict__ W_sum,
    float* __restrict__ out,
    float* __restrict__ pw,       // [NB][D]
    float* __restrict__ pa,       // [NB]
    float* __restrict__ mid,      // [ngrp][D]
    float* __restrict__ mida,     // [ngrp]
    int* __restrict__ gcnt,       // [ngrp+1], pre-zeroed
    int nrows)
{
    const int t    = threadIdx.x;
    const int b    = blockIdx.x;
    const int col4 = t & 31;   // which float4 of the row
    const int rg   = t >> 5;   // row-group 0..7 within the block

    const float4 bwv = reinterpret_cast<const float4*>(bw)[col4];

    float a0 = 0.f, a1 = 0.f, a2 = 0.f, a3 = 0.f;
    float aacc = 0.f;

    const int ftiles = nrows >> 4;          // full 16-row tiles
    const float4* __restrict__ X4 = reinterpret_cast<const float4*>(X);
    const int    gstep = gridDim.x;
    const size_t step  = (size_t)gstep * 512;   // float4 units per stride

    int tile = b;
    if (tile < ftiles) {
        size_t addr = ((size_t)tile * 16 + rg * 2) * 32 + col4;
        float4 x0 = X4[addr];
        float4 x1 = X4[addr + 32];

        while (tile < ftiles) {
            const int ntile = tile + gstep;
            const size_t naddr = addr + (ntile < ftiles ? step : (size_t)0);
            const float4 n0 = X4[naddr];          // clamped prefetch
            const float4 n1 = X4[naddr + 32];

            float d0 = fmaf(x0.x, bwv.x, fmaf(x0.y, bwv.y, fmaf(x0.z, bwv.z, x0.w * bwv.w)));
            float d1 = fmaf(x1.x, bwv.x, fmaf(x1.y, bwv.y, fmaf(x1.z, bwv.z, x1.w * bwv.w)));
            #pragma unroll
            for (int m = 16; m >= 1; m >>= 1) {
                d0 += __shfl_xor(d0, m, 64);
                d1 += __shfl_xor(d1, m, 64);
            }
            const float al0 = __expf(d0);
            const float al1 = __expf(d1);
            aacc += al0 + al1;                    // uniform across the 32 lanes
            a0 = fmaf(al0, x0.x, fmaf(al1, x1.x, a0));
            a1 = fmaf(al0, x0.y, fmaf(al1, x1.y, a1));
            a2 = fmaf(al0, x0.z, fmaf(al1, x1.z, a2));
            a3 = fmaf(al0, x0.w, fmaf(al1, x1.w, a3));

            x0 = n0; x1 = n1; addr = naddr; tile = ntile;
        }
    }

    // remainder rows (nrows % 16): block 0 only — dead for N=200000
    const int rem = nrows & 15;
    if (rem && b == 0) {
        const int r0 = (nrows & ~15) + rg * 2;
        if (r0 < nrows) {
            const float4 x0r = X4[(size_t)r0 * 32 + col4];
            const bool v1 = (r0 + 1) < nrows;
            const float4 x1r = v1 ? X4[(size_t)(r0 + 1) * 32 + col4]
                                  : make_float4(0.f, 0.f, 0.f, 0.f);
            float d0 = fmaf(x0r.x, bwv.x, fmaf(x0r.y, bwv.y, fmaf(x0r.z, bwv.z, x0r.w * bwv.w)));
            float d1 = fmaf(x1r.x, bwv.x, fmaf(x1r.y, bwv.y, fmaf(x1r.z, bwv.z, x1r.w * bwv.w)));
            #pragma unroll
            for (int m = 16; m >= 1; m >>= 1) {
                d0 += __shfl_xor(d0, m, 64);
                d1 += __shfl_xor(d1, m, 64);
            }
            const float al0 = __expf(d0);
            const float al1 = v1 ? __expf(d1) : 0.f;
            aacc += al0 + al1;
            a0 = fmaf(al0, x0r.x, fmaf(al1, x1r.x, a0));
            a1 = fmaf(al0, x0r.y, fmaf(al1, x1r.y, a1));
            a2 = fmaf(al0, x0r.z, fmaf(al1, x1r.z, a2));
            a3 = fmaf(al0, x0r.w, fmaf(al1, x1r.w, a3));
        }
    }

    // -------- block reduction (8 row-groups -> one 128-vector) --------
    __shared__ float red[8][32][4];   // 4 KB
    __shared__ float reda[8];
    red[rg][col4][0] = a0;
    red[rg][col4][1] = a1;
    red[rg][col4][2] = a2;
    red[rg][col4][3] = a3;
    if (col4 == 0) reda[rg] = aacc;
    __syncthreads();

    if (t < D) {
        float s = 0.f;
        #pragma unroll
        for (int r = 0; r < 8; ++r) s += red[r][t >> 2][t & 3];
        pw[(size_t)b * D + t] = s;
    }
    if (t == 0) {
        float s = 0.f;
        #pragma unroll
        for (int r = 0; r < 8; ++r) s += reda[r];
        pa[b] = s;
    }
    __threadfence();     // release partials device-wide
    __syncthreads();

    // -------- group ticket: last block of each 32-block group reduces --------
    __shared__ int tick;
    if (t == 0)
        tick = __hip_atomic_fetch_add(&gcnt[b / GRP], 1,
                                      __ATOMIC_ACQ_REL, __HIP_MEMORY_SCOPE_AGENT);
    __syncthreads();
    if (tick != GRP - 1) return;

    const int ngrp = gridDim.x / GRP;
    const int grp  = b / GRP, g0 = grp * GRP;
    const int k    = t & 127;
    const int h    = t >> 7;          // 0..1

    __shared__ double gredd[2][D];    // 2 KB
    {
        double gs = 0.0;
        for (int j = h * (GRP / 2); j < (h + 1) * (GRP / 2); ++j)
            gs += (double)__hip_atomic_load(&pw[(size_t)(g0 + j) * D + k],
                                            __ATOMIC_RELAXED, __HIP_MEMORY_SCOPE_AGENT);
        gredd[h][k] = gs;

        double ga = 0.0;
        if (t < GRP)
            ga = (double)__hip_atomic_load(&pa[g0 + t],
                                           __ATOMIC_RELAXED, __HIP_MEMORY_SCOPE_AGENT);
        #pragma unroll
        for (int m = 16; m >= 1; m >>= 1) ga += __shfl_xor(ga, m, 64);
        __syncthreads();
        if (t < D) mid[(size_t)grp * D + t] = (float)(gredd[0][t] + gredd[1][t]);
        if (t == 0) mida[grp] = (float)ga;
    }
    __threadfence();
    __syncthreads();

    // -------- global ticket: the last group-reducer does the final --------
    __shared__ int tick2;
    if (t == 0)
        tick2 = __hip_atomic_fetch_add(&gcnt[ngrp], 1,
                                       __ATOMIC_ACQ_REL, __HIP_MEMORY_SCOPE_AGENT);
    __syncthreads();
    if (tick2 != ngrp - 1) return;

    // final: sum mid[ngrp][D] and mida[ngrp]; normalize; @ W_sum
    __shared__ double asum_sh;
    {
        double fs = 0.0;
        for (int j = h; j < ngrp; j += 2)
            fs += (double)__hip_atomic_load(&mid[(size_t)j * D + k],
                                            __ATOMIC_RELAXED, __HIP_MEMORY_SCOPE_AGENT);
        __syncthreads();            // gredd reuse
        gredd[h][k] = fs;

        double fa = 0.0;
        if (t < 64 && t < ngrp)
            fa = (double)__hip_atomic_load(&mida[t],
                                           __ATOMIC_RELAXED, __HIP_MEMORY_SCOPE_AGENT);
        #pragma unroll
        for (int m = 32; m >= 1; m >>= 1) fa += __shfl_xor(fa, m, 64);
        if (t == 0) asum_sh = fa;
    }
    __syncthreads();

    __shared__ float ssh[D];
    if (t < D) ssh[t] = (float)((gredd[0][t] + gredd[1][t]) / asum_sh);
    __syncthreads();

    // out[j] = sum_k ssh[k] * W_sum[k][j]; 2 halves over k, coalesced over j
    float o = 0.f;
    #pragma unroll 8
    for (int kk = h * 64; kk < h * 64 + 64; ++kk)
        o = fmaf(ssh[kk], W_sum[kk * D + k], o);
    __shared__ float rof[2][D];
    rof[h][k] = o;
    __syncthreads();
    if (t < D) out[t] = rof[0][t] + rof[1][t];
}

// ---------------------------------------------------------------------------
extern "C" void kernel_launch(void* const* d_in, const int* in_sizes, int n_in,
                              void* d_out, int out_size, void* d_ws, size_t ws_size,
                              hipStream_t stream) {
    const float* X       = (const float*)d_in[0];
    const float* W_sum   = (const float*)d_in[1];
    const float* W_alpha = (const float*)d_in[2];
    const float* b_alpha = (const float*)d_in[4];
    float* out = (float*)d_out;

    const int nrows = in_sizes[0] / D;   // 200000

    int NB = 2048;                        // multiple of GRP
    auto need = [&](int nb) {
        const int ng = nb / GRP;
        return (size_t)nb * (D + 1) * sizeof(float)      // pw + pa
             + 256
             + (size_t)ng * (D + 1) * sizeof(float)      // mid + mida
             + (D + 4) * sizeof(float)                   // bw
             + (size_t)(ng + 1) * sizeof(int) + 256;     // counters
    };
    while (NB > GRP && need(NB) > ws_size) NB >>= 1;
    const int ngrp = NB / GRP;

    char* ws = (char*)d_ws;
    float* pw   = (float*)ws;
    float* pa   = pw + (size_t)NB * D;
    size_t off = ((size_t)NB * (D + 1) * sizeof(float) + 255) & ~(size_t)255;
    float* mid  = (float*)(ws + off);
    float* mida = mid + (size_t)ngrp * D;
    float* bw   = mida + ngrp;
    size_t off2 = (off + (size_t)ngrp * (D + 1) * sizeof(float)
                       + (D + 4) * sizeof(float) + 255) & ~(size_t)255;
    int*   gcnt = (int*)(ws + off2);

    prep_kernel<<<1, 1024, 0, stream>>>(W_alpha, b_alpha, bw, gcnt, ngrp);
    main_pass_kernel<<<NB, 256, 0, stream>>>(X, bw, W_sum, out, pw, pa,
                                             mid, mida, gcnt, nrows);
}

// Round 10
// 40.219 us; speedup vs baseline: 6.3278x; 6.3278x over previous
//
#include <hip/hip_runtime.h>
#include <hip/hip_bf16.h>

#define D 128

// ---------------------------------------------------------------------------
// alpha_j = exp(c + b_w.X[j]); c cancels in the normalization => only
// b_w = b_alpha^T W_alpha matters.
//
// Structure (4 dispatches, no cross-block sync anywhere):
//  prep (8 blocks):  b_w = b_alpha^T W_alpha (16 cols per block).
//  main (2048 blk):  stream X once (measured ~15 us, ~7 TB/s); per-block
//                    partial (sum_j alpha_j X_j, sum_j alpha_j) -> pw/pa.
//  r1m  (64 blocks): group-reduce 32 partials AND apply W_sum matvec to the
//                    group sum (linearity: out = sum_b (pw_b @ W_sum)/asum),
//                    so W_sum is read by 64 blocks in parallel.
//  fin  (1 block):   sum 64 transformed vectors + 64 alpha scalars, divide.
// All reduction orders fixed -> bit-identical across replays.
// ---------------------------------------------------------------------------

// Kernel 1 (8 blocks, 256 threads): b_w = b_alpha^T @ W_alpha.
__global__ __launch_bounds__(256) void prep_kernel(
    const float* __restrict__ W_alpha,
    const float* __restrict__ b_alpha,
    float* __restrict__ bw_out)   // [D]
{
    const int t  = threadIdx.x;
    const int kk = blockIdx.x * 16 + (t & 15);   // output column
    const int gg = t >> 4;                       // 0..15: 8 i-terms each
    float s = 0.f;
    #pragma unroll
    for (int i = gg * 8; i < gg * 8 + 8; ++i)
        s = fmaf(b_alpha[i], W_alpha[i * D + kk], s);
    __shared__ float sA[16][17];
    sA[gg][t & 15] = s;
    __syncthreads();
    if (t < 16) {
        float r = 0.f;
        #pragma unroll
        for (int g2 = 0; g2 < 16; ++g2) r += sA[g2][t];
        bw_out[blockIdx.x * 16 + t] = r;
    }
}

// ---------------------------------------------------------------------------
// Kernel 2 (main pass): R5 loop verbatim — branchless streaming, 2 rows per
// 32-lane subgroup, depth-1 clamped prefetch. Measured ~15 us.
// ---------------------------------------------------------------------------
__global__ __launch_bounds__(256, 8) void main_pass_kernel(
    const float* __restrict__ X,
    const float* __restrict__ bw,
    float* __restrict__ partial_wsum,    // [gridDim.x][D]
    float* __restrict__ partial_alpha,   // [gridDim.x]
    int nrows)
{
    const int t    = threadIdx.x;
    const int col4 = t & 31;   // which float4 of the row
    const int rg   = t >> 5;   // row-group 0..7 within the block

    const float4 bwv = reinterpret_cast<const float4*>(bw)[col4];

    float a0 = 0.f, a1 = 0.f, a2 = 0.f, a3 = 0.f;
    float aacc = 0.f;

    const int ftiles = nrows >> 4;          // full 16-row tiles
    const float4* __restrict__ X4 = reinterpret_cast<const float4*>(X);
    const int    gstep = gridDim.x;
    const size_t step  = (size_t)gstep * 512;   // float4 units per stride

    int tile = blockIdx.x;
    if (tile < ftiles) {
        size_t addr = ((size_t)tile * 16 + rg * 2) * 32 + col4;
        float4 x0 = X4[addr];
        float4 x1 = X4[addr + 32];

        while (tile < ftiles) {
            const int ntile = tile + gstep;
            const size_t naddr = addr + (ntile < ftiles ? step : (size_t)0);
            const float4 n0 = X4[naddr];          // clamped prefetch
            const float4 n1 = X4[naddr + 32];

            float d0 = fmaf(x0.x, bwv.x, fmaf(x0.y, bwv.y, fmaf(x0.z, bwv.z, x0.w * bwv.w)));
            float d1 = fmaf(x1.x, bwv.x, fmaf(x1.y, bwv.y, fmaf(x1.z, bwv.z, x1.w * bwv.w)));
            #pragma unroll
            for (int m = 16; m >= 1; m >>= 1) {
                d0 += __shfl_xor(d0, m, 64);
                d1 += __shfl_xor(d1, m, 64);
            }
            const float al0 = __expf(d0);
            const float al1 = __expf(d1);
            aacc += al0 + al1;                    // uniform across the 32 lanes
            a0 = fmaf(al0, x0.x, fmaf(al1, x1.x, a0));
            a1 = fmaf(al0, x0.y, fmaf(al1, x1.y, a1));
            a2 = fmaf(al0, x0.z, fmaf(al1, x1.z, a2));
            a3 = fmaf(al0, x0.w, fmaf(al1, x1.w, a3));

            x0 = n0; x1 = n1; addr = naddr; tile = ntile;
        }
    }

    // remainder rows (nrows % 16): block 0 only — dead for N=200000
    const int rem = nrows & 15;
    if (rem && blockIdx.x == 0) {
        const int r0 = (nrows & ~15) + rg * 2;
        if (r0 < nrows) {
            const float4 x0r = X4[(size_t)r0 * 32 + col4];
            const bool v1 = (r0 + 1) < nrows;
            const float4 x1r = v1 ? X4[(size_t)(r0 + 1) * 32 + col4]
                                  : make_float4(0.f, 0.f, 0.f, 0.f);
            float d0 = fmaf(x0r.x, bwv.x, fmaf(x0r.y, bwv.y, fmaf(x0r.z, bwv.z, x0r.w * bwv.w)));
            float d1 = fmaf(x1r.x, bwv.x, fmaf(x1r.y, bwv.y, fmaf(x1r.z, bwv.z, x1r.w * bwv.w)));
            #pragma unroll
            for (int m = 16; m >= 1; m >>= 1) {
                d0 += __shfl_xor(d0, m, 64);
                d1 += __shfl_xor(d1, m, 64);
            }
            const float al0 = __expf(d0);
            const float al1 = v1 ? __expf(d1) : 0.f;
            aacc += al0 + al1;
            a0 = fmaf(al0, x0r.x, fmaf(al1, x1r.x, a0));
            a1 = fmaf(al0, x0r.y, fmaf(al1, x1r.y, a1));
            a2 = fmaf(al0, x0r.z, fmaf(al1, x1r.z, a2));
            a3 = fmaf(al0, x0r.w, fmaf(al1, x1r.w, a3));
        }
    }

    // -------- block reduction (8 row-groups -> one 128-vector) --------
    __shared__ float red[8][32][4];   // 4 KB
    __shared__ float reda[8];
    red[rg][col4][0] = a0;
    red[rg][col4][1] = a1;
    red[rg][col4][2] = a2;
    red[rg][col4][3] = a3;
    if (col4 == 0) reda[rg] = aacc;
    __syncthreads();

    if (t < D) {
        float s = 0.f;
        #pragma unroll
        for (int r = 0; r < 8; ++r) s += red[r][t >> 2][t & 3];
        partial_wsum[(size_t)blockIdx.x * D + t] = s;
    }
    if (t == 0) {
        float s = 0.f;
        #pragma unroll
        for (int r = 0; r < 8; ++r) s += reda[r];
        partial_alpha[blockIdx.x] = s;
    }
}

// ---------------------------------------------------------------------------
// Kernel 3 (64 blocks, 512 threads): group-reduce nper partials, then apply
// the W_sum matvec to the group sum. ovec[b] = (sum of group b's pw) @ W_sum,
// ga[b] = sum of group b's pa.
// ---------------------------------------------------------------------------
__global__ __launch_bounds__(512) void r1m_kernel(
    const float* __restrict__ partial_wsum,   // [NB][D]
    const float* __restrict__ partial_alpha,  // [NB]
    const float* __restrict__ W_sum,          // [D][D]
    float* __restrict__ ovec,                 // [64][D]
    float* __restrict__ ga,                   // [64]
    int NB)
{
    const int b  = blockIdx.x;
    const int t  = threadIdx.x;
    const int k  = t & 127;
    const int rs = t >> 7;        // 0..3
    const int nper = NB >> 6;     // NB/64

    // ---- weighted-sum group reduce (rows b + 64*j) ----
    double s = 0.0;
    for (int j = rs; j < nper; j += 4)
        s += (double)partial_wsum[(size_t)(b + 64 * j) * D + k];  // coalesced
    __shared__ double red[4][D];  // 4 KB
    red[rs][k] = s;

    // ---- alpha group reduce (wave 0) ----
    double ap = 0.0;
    if (t < 64) {
        for (int j = t; j < nper; j += 64)
            ap += (double)partial_alpha[b + 64 * j];
        #pragma unroll
        for (int m = 32; m >= 1; m >>= 1) ap += __shfl_xor(ap, m, 64);
        if (t == 0) ga[b] = (float)ap;
    }
    __syncthreads();

    __shared__ float mid_sh[D];
    if (t < D) mid_sh[t] = (float)(red[0][t] + red[1][t] + red[2][t] + red[3][t]);
    __syncthreads();

    // ---- matvec: o[j] = sum_k mid[k] * W_sum[k][j], 4 k-chunks ----
    float o = 0.f;
    #pragma unroll 8
    for (int kk = rs * 32; kk < rs * 32 + 32; ++kk)
        o = fmaf(mid_sh[kk], W_sum[kk * D + k], o);   // coalesced across k
    __shared__ float rout[4][D];  // 2 KB
    rout[rs][k] = o;
    __syncthreads();
    if (t < D)
        ovec[(size_t)b * D + t] = rout[0][t] + rout[1][t] + rout[2][t] + rout[3][t];
}

// ---------------------------------------------------------------------------
// Kernel 4 (1 block, 256 threads): out[j] = (sum_b ovec[b][j]) / (sum_b ga[b]).
// Reads 32 KB + 256 B.
// ---------------------------------------------------------------------------
__global__ __launch_bounds__(256) void fin_kernel(
    const float* __restrict__ ovec,   // [64][D]
    const float* __restrict__ ga,     // [64]
    float* __restrict__ out)
{
    const int t = threadIdx.x;
    const int k = t & 127;
    const int h = t >> 7;     // 0..1

    double s = 0.0;
    for (int b = h; b < 64; b += 2)
        s += (double)ovec[(size_t)b * D + k];   // coalesced across k
    __shared__ double red[2][D];   // 2 KB
    red[h][k] = s;

    __shared__ double asum_sh;
    if (t < 64) {
        double a = (double)ga[t];
        #pragma unroll
        for (int m = 32; m >= 1; m >>= 1) a += __shfl_xor(a, m, 64);
        if (t == 0) asum_sh = a;
    }
    __syncthreads();

    if (t < D)
        out[t] = (float)((red[0][t] + red[1][t]) / asum_sh);
}

// ---------------------------------------------------------------------------
extern "C" void kernel_launch(void* const* d_in, const int* in_sizes, int n_in,
                              void* d_out, int out_size, void* d_ws, size_t ws_size,
                              hipStream_t stream) {
    const float* X       = (const float*)d_in[0];
    const float* W_sum   = (const float*)d_in[1];
    const float* W_alpha = (const float*)d_in[2];
    const float* b_alpha = (const float*)d_in[4];
    float* out = (float*)d_out;

    const int nrows = in_sizes[0] / D;   // 200000

    int NB = 2048;                       // multiple of 64
    auto need = [&](int nb) {
        return (size_t)nb * (D + 1) * sizeof(float)    // pw + pa
             + 256
             + (size_t)64 * (D + 1) * sizeof(float)    // ovec + ga
             + (D + 4) * sizeof(float);                // bw
    };
    while (NB > 64 && need(NB) > ws_size) NB >>= 1;

    char* ws = (char*)d_ws;
    float* pw   = (float*)ws;
    float* pa   = pw + (size_t)NB * D;
    size_t off = ((size_t)NB * (D + 1) * sizeof(float) + 255) & ~(size_t)255;
    float* ovec = (float*)(ws + off);
    float* ga   = ovec + (size_t)64 * D;
    float* bw   = ga + 64;

    prep_kernel<<<8, 256, 0, stream>>>(W_alpha, b_alpha, bw);
    main_pass_kernel<<<NB, 256, 0, stream>>>(X, bw, pw, pa, nrows);
    r1m_kernel<<<64, 512, 0, stream>>>(pw, pa, W_sum, ovec, ga, NB);
    fin_kernel<<<1, 256, 0, stream>>>(ovec, ga, out);
}

// Round 11
// 32.974 us; speedup vs baseline: 7.7180x; 1.2197x over previous
//
#include <hip/hip_runtime.h>
#include <hip/hip_bf16.h>

#define D 128
#define FIXS 1099511627776.0   // 2^40 fixed-point scale (int64 atomics: exact, order-independent)

// ---------------------------------------------------------------------------
// alpha_j = exp(c + b_w.X[j]); c cancels in the normalization => only
// b_w = b_alpha^T W_alpha is needed.
//
// 3 dispatches:
//  prep (1 blk):   b_w = b_alpha^T W_alpha; zero int64 accumulators + ticket.
//  main (2048 blk): stream X once (~15 us measured, ~7 TB/s) -> pw/pa.
//  r1mf (64 blk):  group-reduce 32 partials, apply W_sum matvec (W_sum loads
//                  issued FIRST, staged to LDS -> overlap with reduce),
//                  accumulate numerator/denominator as fixed-point int64
//                  atomics (deterministic: integer adds are associative);
//                  64-block ticket -> last block divides and stores out.
// ---------------------------------------------------------------------------

// Kernel 1 (1 block, 1024 threads)
__global__ __launch_bounds__(1024) void prep_kernel(
    const float* __restrict__ W_alpha,
    const float* __restrict__ b_alpha,
    float* __restrict__ bw_out,          // [D]
    long long* __restrict__ oacc,        // [D+1] fixed-point accumulators
    int* __restrict__ gcnt)              // [1] ticket
{
    const int t = threadIdx.x;
    if (t < D + 1) oacc[t] = 0;
    if (t == D + 1) gcnt[0] = 0;

    const int k = t & 127;        // output column
    const int g = t >> 7;         // 0..7: 16 i-terms each
    __shared__ float bal[D];
    if (t < D) bal[t] = b_alpha[t];
    __syncthreads();

    float bw = 0.f;
    #pragma unroll
    for (int i = g * 16; i < g * 16 + 16; ++i)
        bw = fmaf(bal[i], W_alpha[i * D + k], bw);   // coalesced across k

    __shared__ float rbw[8][D];
    rbw[g][k] = bw;
    __syncthreads();
    if (t < D) {
        float B = 0.f;
        #pragma unroll
        for (int r = 0; r < 8; ++r) B += rbw[r][t];
        bw_out[t] = B;
    }
}

// ---------------------------------------------------------------------------
// Kernel 2: R5 main loop verbatim (measured ~15 us, at the BW ceiling).
// ---------------------------------------------------------------------------
__global__ __launch_bounds__(256, 8) void main_pass_kernel(
    const float* __restrict__ X,
    const float* __restrict__ bw,
    float* __restrict__ partial_wsum,    // [gridDim.x][D]
    float* __restrict__ partial_alpha,   // [gridDim.x]
    int nrows)
{
    const int t    = threadIdx.x;
    const int col4 = t & 31;   // which float4 of the row
    const int rg   = t >> 5;   // row-group 0..7 within the block

    const float4 bwv = reinterpret_cast<const float4*>(bw)[col4];

    float a0 = 0.f, a1 = 0.f, a2 = 0.f, a3 = 0.f;
    float aacc = 0.f;

    const int ftiles = nrows >> 4;          // full 16-row tiles
    const float4* __restrict__ X4 = reinterpret_cast<const float4*>(X);
    const int    gstep = gridDim.x;
    const size_t step  = (size_t)gstep * 512;   // float4 units per stride

    int tile = blockIdx.x;
    if (tile < ftiles) {
        size_t addr = ((size_t)tile * 16 + rg * 2) * 32 + col4;
        float4 x0 = X4[addr];
        float4 x1 = X4[addr + 32];

        while (tile < ftiles) {
            const int ntile = tile + gstep;
            const size_t naddr = addr + (ntile < ftiles ? step : (size_t)0);
            const float4 n0 = X4[naddr];          // clamped prefetch
            const float4 n1 = X4[naddr + 32];

            float d0 = fmaf(x0.x, bwv.x, fmaf(x0.y, bwv.y, fmaf(x0.z, bwv.z, x0.w * bwv.w)));
            float d1 = fmaf(x1.x, bwv.x, fmaf(x1.y, bwv.y, fmaf(x1.z, bwv.z, x1.w * bwv.w)));
            #pragma unroll
            for (int m = 16; m >= 1; m >>= 1) {
                d0 += __shfl_xor(d0, m, 64);
                d1 += __shfl_xor(d1, m, 64);
            }
            const float al0 = __expf(d0);
            const float al1 = __expf(d1);
            aacc += al0 + al1;                    // uniform across the 32 lanes
            a0 = fmaf(al0, x0.x, fmaf(al1, x1.x, a0));
            a1 = fmaf(al0, x0.y, fmaf(al1, x1.y, a1));
            a2 = fmaf(al0, x0.z, fmaf(al1, x1.z, a2));
            a3 = fmaf(al0, x0.w, fmaf(al1, x1.w, a3));

            x0 = n0; x1 = n1; addr = naddr; tile = ntile;
        }
    }

    // remainder rows (nrows % 16): block 0 only — dead for N=200000
    const int rem = nrows & 15;
    if (rem && blockIdx.x == 0) {
        const int r0 = (nrows & ~15) + rg * 2;
        if (r0 < nrows) {
            const float4 x0r = X4[(size_t)r0 * 32 + col4];
            const bool v1 = (r0 + 1) < nrows;
            const float4 x1r = v1 ? X4[(size_t)(r0 + 1) * 32 + col4]
                                  : make_float4(0.f, 0.f, 0.f, 0.f);
            float d0 = fmaf(x0r.x, bwv.x, fmaf(x0r.y, bwv.y, fmaf(x0r.z, bwv.z, x0r.w * bwv.w)));
            float d1 = fmaf(x1r.x, bwv.x, fmaf(x1r.y, bwv.y, fmaf(x1r.z, bwv.z, x1r.w * bwv.w)));
            #pragma unroll
            for (int m = 16; m >= 1; m >>= 1) {
                d0 += __shfl_xor(d0, m, 64);
                d1 += __shfl_xor(d1, m, 64);
            }
            const float al0 = __expf(d0);
            const float al1 = v1 ? __expf(d1) : 0.f;
            aacc += al0 + al1;
            a0 = fmaf(al0, x0r.x, fmaf(al1, x1r.x, a0));
            a1 = fmaf(al0, x0r.y, fmaf(al1, x1r.y, a1));
            a2 = fmaf(al0, x0r.z, fmaf(al1, x1r.z, a2));
            a3 = fmaf(al0, x0r.w, fmaf(al1, x1r.w, a3));
        }
    }

    // -------- block reduction (8 row-groups -> one 128-vector) --------
    __shared__ float red[8][32][4];   // 4 KB
    __shared__ float reda[8];
    red[rg][col4][0] = a0;
    red[rg][col4][1] = a1;
    red[rg][col4][2] = a2;
    red[rg][col4][3] = a3;
    if (col4 == 0) reda[rg] = aacc;
    __syncthreads();

    if (t < D) {
        float s = 0.f;
        #pragma unroll
        for (int r = 0; r < 8; ++r) s += red[r][t >> 2][t & 3];
        partial_wsum[(size_t)blockIdx.x * D + t] = s;
    }
    if (t == 0) {
        float s = 0.f;
        #pragma unroll
        for (int r = 0; r < 8; ++r) s += reda[r];
        partial_alpha[blockIdx.x] = s;
    }
}

// ---------------------------------------------------------------------------
// Kernel 3 (64 blocks, 512 threads): group-reduce + matvec + int64-atomic
// gather; last-ticket block divides and writes out.
// ---------------------------------------------------------------------------
__global__ __launch_bounds__(512) void r1mf_kernel(
    const float* __restrict__ partial_wsum,   // [NB][D]
    const float* __restrict__ partial_alpha,  // [NB]
    const float* __restrict__ W_sum,          // [D][D]
    long long* __restrict__ oacc,             // [D+1], pre-zeroed
    int* __restrict__ gcnt,                   // [1], pre-zeroed
    float* __restrict__ out,
    int NB)
{
    const int b  = blockIdx.x;
    const int t  = threadIdx.x;
    const int k  = t & 127;
    const int rs = t >> 7;        // 0..3
    const int nper = NB >> 6;     // NB/64

    // ---- issue W_sum loads FIRST (8 float4/thread = full 64 KB) ----
    const float4* __restrict__ W4 = reinterpret_cast<const float4*>(W_sum);
    float4 w[8];
    #pragma unroll
    for (int i = 0; i < 8; ++i) w[i] = W4[t + 512 * i];

    // ---- group-reduce pw rows {b + 64*j} while W_sum is in flight ----
    double s = 0.0;
    #pragma unroll 4
    for (int j = rs; j < nper; j += 4)
        s += (double)partial_wsum[(size_t)(b + 64 * j) * D + k];  // coalesced
    __shared__ double red[4][D];  // 4 KB
    red[rs][k] = s;

    // ---- alpha group reduce (wave 0) ----
    __shared__ float ga_sh;
    if (t < 64) {
        double ap = 0.0;
        for (int j = t; j < nper; j += 64)
            ap += (double)partial_alpha[b + 64 * j];
        #pragma unroll
        for (int m = 32; m >= 1; m >>= 1) ap += __shfl_xor(ap, m, 64);
        if (t == 0) ga_sh = (float)ap;
    }

    // ---- stage W_sum to LDS ----
    __shared__ float wls[D * D];  // 64 KB
    float4* wls4 = reinterpret_cast<float4*>(wls);
    #pragma unroll
    for (int i = 0; i < 8; ++i) wls4[t + 512 * i] = w[i];
    __syncthreads();

    __shared__ float mid_sh[D];
    if (t < D)
        mid_sh[t] = (float)(red[0][t] + red[1][t] + red[2][t] + red[3][t]);
    __syncthreads();

    // ---- matvec: o[j] = sum_k mid[k] * W_sum[k][j], 4 k-chunks ----
    float o = 0.f;
    #pragma unroll 8
    for (int kk = rs * 32; kk < rs * 32 + 32; ++kk)
        o = fmaf(mid_sh[kk], wls[kk * D + k], o);
    __shared__ float rout[4][D];  // 2 KB
    rout[rs][k] = o;
    __syncthreads();

    // ---- fixed-point int64 atomic gather (deterministic) ----
    if (t < D) {
        const float of = rout[0][t] + rout[1][t] + rout[2][t] + rout[3][t];
        const long long fx = (long long)llrint((double)of * FIXS);
        __hip_atomic_fetch_add(&oacc[t], fx, __ATOMIC_RELAXED,
                               __HIP_MEMORY_SCOPE_AGENT);
    }
    if (t == 0) {
        const long long fa = (long long)llrint((double)ga_sh * FIXS);
        __hip_atomic_fetch_add(&oacc[D], fa, __ATOMIC_RELAXED,
                               __HIP_MEMORY_SCOPE_AGENT);
    }
    __syncthreads();

    // ---- ticket: last of 64 blocks divides and stores ----
    __shared__ int tick_sh;
    if (t == 0) {
        __threadfence();
        tick_sh = __hip_atomic_fetch_add(gcnt, 1, __ATOMIC_ACQ_REL,
                                         __HIP_MEMORY_SCOPE_AGENT);
    }
    __syncthreads();
    if (tick_sh != 63) return;

    __shared__ double asum_d;
    if (t == 0)
        asum_d = (double)__hip_atomic_load(&oacc[D], __ATOMIC_RELAXED,
                                           __HIP_MEMORY_SCOPE_AGENT);
    __syncthreads();
    if (t < D) {
        const long long num = __hip_atomic_load(&oacc[t], __ATOMIC_RELAXED,
                                                __HIP_MEMORY_SCOPE_AGENT);
        out[t] = (float)((double)num / asum_d);
    }
}

// ---------------------------------------------------------------------------
extern "C" void kernel_launch(void* const* d_in, const int* in_sizes, int n_in,
                              void* d_out, int out_size, void* d_ws, size_t ws_size,
                              hipStream_t stream) {
    const float* X       = (const float*)d_in[0];
    const float* W_sum   = (const float*)d_in[1];
    const float* W_alpha = (const float*)d_in[2];
    const float* b_alpha = (const float*)d_in[4];
    float* out = (float*)d_out;

    const int nrows = in_sizes[0] / D;   // 200000

    int NB = 2048;                       // multiple of 64
    auto need = [&](int nb) {
        return (size_t)nb * (D + 1) * sizeof(float)    // pw + pa
             + 256 + (D + 4) * sizeof(float)           // bw
             + 256 + (D + 1) * sizeof(long long)       // oacc
             + sizeof(int) + 64;                       // gcnt
    };
    while (NB > 64 && need(NB) > ws_size) NB >>= 1;

    char* ws = (char*)d_ws;
    float* pw = (float*)ws;
    float* pa = pw + (size_t)NB * D;
    size_t off = ((size_t)NB * (D + 1) * sizeof(float) + 255) & ~(size_t)255;
    float* bw = (float*)(ws + off);
    size_t off2 = (off + (D + 4) * sizeof(float) + 255) & ~(size_t)255;
    long long* oacc = (long long*)(ws + off2);
    int* gcnt = (int*)(oacc + (D + 1));

    prep_kernel<<<1, 1024, 0, stream>>>(W_alpha, b_alpha, bw, oacc, gcnt);
    main_pass_kernel<<<NB, 256, 0, stream>>>(X, bw, pw, pa, nrows);
    r1mf_kernel<<<64, 512, 0, stream>>>(pw, pa, W_sum, oacc, gcnt, out, NB);
}

// Round 12
// 32.844 us; speedup vs baseline: 7.7486x; 1.0040x over previous
//
#include <hip/hip_runtime.h>
#include <hip/hip_bf16.h>

#define D 128
#define FIXS 1099511627776.0   // 2^40 fixed-point scale (int64 atomics: exact, order-independent)

// ---------------------------------------------------------------------------
// alpha_j = exp(c + b_w.X[j]); c cancels in the normalization => only
// b_w = b_alpha^T W_alpha is needed.
//
// 3 dispatches:
//  prep (8 blk):   b_w = b_alpha^T W_alpha (16 cols/block); block 0 zeroes
//                  the int64 accumulators + ticket.
//  main (2048 blk): stream X once; 4 rows per 32-lane subgroup per iteration
//                  (4 independent load+dot chains -> 2x in-flight bytes vs
//                  R11), depth-1 clamped prefetch, branchless.
//  r1mf (64 blk):  group-reduce 32 partials, W_sum matvec (loads issued
//                  first, staged to LDS), fixed-point int64 atomic gather;
//                  last-ticket block divides and stores.
// All arithmetic orders fixed or integer-associative -> bit-stable replays.
// ---------------------------------------------------------------------------

// Kernel 1 (8 blocks, 256 threads): b_w; block 0 zeroes counters.
__global__ __launch_bounds__(256) void prep_kernel(
    const float* __restrict__ W_alpha,
    const float* __restrict__ b_alpha,
    float* __restrict__ bw_out,          // [D]
    long long* __restrict__ oacc,        // [D+1]
    int* __restrict__ gcnt)              // [1]
{
    const int t = threadIdx.x;
    if (blockIdx.x == 0) {
        if (t < D + 1) oacc[t] = 0;
        if (t == D + 1) gcnt[0] = 0;
    }
    const int kk = blockIdx.x * 16 + (t & 15);   // output column
    const int gg = t >> 4;                       // 0..15: 8 i-terms each
    float s = 0.f;
    #pragma unroll
    for (int i = gg * 8; i < gg * 8 + 8; ++i)
        s = fmaf(b_alpha[i], W_alpha[i * D + kk], s);
    __shared__ float sA[16][17];
    sA[gg][t & 15] = s;
    __syncthreads();
    if (t < 16) {
        float r = 0.f;
        #pragma unroll
        for (int g2 = 0; g2 < 16; ++g2) r += sA[g2][t];
        bw_out[blockIdx.x * 16 + t] = r;
    }
}

// ---------------------------------------------------------------------------
// Kernel 2 (main pass): 4 rows per 32-lane subgroup per iteration.
// ---------------------------------------------------------------------------
__global__ __launch_bounds__(256, 8) void main_pass_kernel(
    const float* __restrict__ X,
    const float* __restrict__ bw,
    float* __restrict__ partial_wsum,    // [gridDim.x][D]
    float* __restrict__ partial_alpha,   // [gridDim.x]
    int nrows)
{
    const int t    = threadIdx.x;
    const int col4 = t & 31;   // which float4 of the row
    const int rg   = t >> 5;   // row-group 0..7 within the block

    const float4 bwv = reinterpret_cast<const float4*>(bw)[col4];

    float a0 = 0.f, a1 = 0.f, a2 = 0.f, a3 = 0.f;
    float aacc = 0.f;

    const int ftiles = nrows >> 5;          // full 32-row tiles
    const float4* __restrict__ X4 = reinterpret_cast<const float4*>(X);
    const int    gstep = gridDim.x;
    const size_t step  = (size_t)gstep * 1024;  // float4 units per stride

    int tile = blockIdx.x;
    if (tile < ftiles) {
        size_t addr = ((size_t)tile * 32 + rg * 4) * 32 + col4;
        float4 x0 = X4[addr];
        float4 x1 = X4[addr + 32];
        float4 x2 = X4[addr + 64];
        float4 x3 = X4[addr + 96];

        while (tile < ftiles) {
            const int ntile = tile + gstep;
            const size_t naddr = addr + (ntile < ftiles ? step : (size_t)0);
            const float4 n0 = X4[naddr];          // clamped prefetch
            const float4 n1 = X4[naddr + 32];
            const float4 n2 = X4[naddr + 64];
            const float4 n3 = X4[naddr + 96];

            float d0 = fmaf(x0.x, bwv.x, fmaf(x0.y, bwv.y, fmaf(x0.z, bwv.z, x0.w * bwv.w)));
            float d1 = fmaf(x1.x, bwv.x, fmaf(x1.y, bwv.y, fmaf(x1.z, bwv.z, x1.w * bwv.w)));
            float d2 = fmaf(x2.x, bwv.x, fmaf(x2.y, bwv.y, fmaf(x2.z, bwv.z, x2.w * bwv.w)));
            float d3 = fmaf(x3.x, bwv.x, fmaf(x3.y, bwv.y, fmaf(x3.z, bwv.z, x3.w * bwv.w)));
            #pragma unroll
            for (int m = 16; m >= 1; m >>= 1) {
                d0 += __shfl_xor(d0, m, 64);
                d1 += __shfl_xor(d1, m, 64);
                d2 += __shfl_xor(d2, m, 64);
                d3 += __shfl_xor(d3, m, 64);
            }
            const float al0 = __expf(d0);
            const float al1 = __expf(d1);
            const float al2 = __expf(d2);
            const float al3 = __expf(d3);
            aacc += (al0 + al1) + (al2 + al3);    // uniform across 32 lanes
            a0 = fmaf(al0, x0.x, fmaf(al1, x1.x, fmaf(al2, x2.x, fmaf(al3, x3.x, a0))));
            a1 = fmaf(al0, x0.y, fmaf(al1, x1.y, fmaf(al2, x2.y, fmaf(al3, x3.y, a1))));
            a2 = fmaf(al0, x0.z, fmaf(al1, x1.z, fmaf(al2, x2.z, fmaf(al3, x3.z, a2))));
            a3 = fmaf(al0, x0.w, fmaf(al1, x1.w, fmaf(al2, x2.w, fmaf(al3, x3.w, a3))));

            x0 = n0; x1 = n1; x2 = n2; x3 = n3;
            addr = naddr; tile = ntile;
        }
    }

    // remainder rows (nrows % 32): block 0, 1 row per subgroup — dead for N=200000
    const int rem = nrows & 31;
    if (rem && blockIdx.x == 0) {
        const int base = nrows & ~31;
        for (int r = base + rg; r < nrows; r += 8) {
            const float4 x = X4[(size_t)r * 32 + col4];
            float d = fmaf(x.x, bwv.x, fmaf(x.y, bwv.y, fmaf(x.z, bwv.z, x.w * bwv.w)));
            #pragma unroll
            for (int m = 16; m >= 1; m >>= 1) d += __shfl_xor(d, m, 64);
            const float al = __expf(d);
            aacc += al;
            a0 = fmaf(al, x.x, a0);
            a1 = fmaf(al, x.y, a1);
            a2 = fmaf(al, x.z, a2);
            a3 = fmaf(al, x.w, a3);
        }
    }

    // -------- block reduction (8 row-groups -> one 128-vector) --------
    __shared__ float red[8][32][4];   // 4 KB
    __shared__ float reda[8];
    red[rg][col4][0] = a0;
    red[rg][col4][1] = a1;
    red[rg][col4][2] = a2;
    red[rg][col4][3] = a3;
    if (col4 == 0) reda[rg] = aacc;
    __syncthreads();

    if (t < D) {
        float s = 0.f;
        #pragma unroll
        for (int r = 0; r < 8; ++r) s += red[r][t >> 2][t & 3];
        partial_wsum[(size_t)blockIdx.x * D + t] = s;
    }
    if (t == 0) {
        float s = 0.f;
        #pragma unroll
        for (int r = 0; r < 8; ++r) s += reda[r];
        partial_alpha[blockIdx.x] = s;
    }
}

// ---------------------------------------------------------------------------
// Kernel 3 (64 blocks, 512 threads): group-reduce + matvec + int64-atomic
// gather; last-ticket block divides and writes out. (R11 verbatim.)
// ---------------------------------------------------------------------------
__global__ __launch_bounds__(512) void r1mf_kernel(
    const float* __restrict__ partial_wsum,   // [NB][D]
    const float* __restrict__ partial_alpha,  // [NB]
    const float* __restrict__ W_sum,          // [D][D]
    long long* __restrict__ oacc,             // [D+1], pre-zeroed
    int* __restrict__ gcnt,                   // [1], pre-zeroed
    float* __restrict__ out,
    int NB)
{
    const int b  = blockIdx.x;
    const int t  = threadIdx.x;
    const int k  = t & 127;
    const int rs = t >> 7;        // 0..3
    const int nper = NB >> 6;     // NB/64

    // ---- issue W_sum loads FIRST (8 float4/thread = full 64 KB) ----
    const float4* __restrict__ W4 = reinterpret_cast<const float4*>(W_sum);
    float4 w[8];
    #pragma unroll
    for (int i = 0; i < 8; ++i) w[i] = W4[t + 512 * i];

    // ---- group-reduce pw rows {b + 64*j} while W_sum is in flight ----
    double s = 0.0;
    #pragma unroll 4
    for (int j = rs; j < nper; j += 4)
        s += (double)partial_wsum[(size_t)(b + 64 * j) * D + k];  // coalesced
    __shared__ double red[4][D];  // 4 KB
    red[rs][k] = s;

    // ---- alpha group reduce (wave 0) ----
    __shared__ float ga_sh;
    if (t < 64) {
        double ap = 0.0;
        for (int j = t; j < nper; j += 64)
            ap += (double)partial_alpha[b + 64 * j];
        #pragma unroll
        for (int m = 32; m >= 1; m >>= 1) ap += __shfl_xor(ap, m, 64);
        if (t == 0) ga_sh = (float)ap;
    }

    // ---- stage W_sum to LDS ----
    __shared__ float wls[D * D];  // 64 KB
    float4* wls4 = reinterpret_cast<float4*>(wls);
    #pragma unroll
    for (int i = 0; i < 8; ++i) wls4[t + 512 * i] = w[i];
    __syncthreads();

    __shared__ float mid_sh[D];
    if (t < D)
        mid_sh[t] = (float)(red[0][t] + red[1][t] + red[2][t] + red[3][t]);
    __syncthreads();

    // ---- matvec: o[j] = sum_k mid[k] * W_sum[k][j], 4 k-chunks ----
    float o = 0.f;
    #pragma unroll 8
    for (int kk = rs * 32; kk < rs * 32 + 32; ++kk)
        o = fmaf(mid_sh[kk], wls[kk * D + k], o);
    __shared__ float rout[4][D];  // 2 KB
    rout[rs][k] = o;
    __syncthreads();

    // ---- fixed-point int64 atomic gather (deterministic) ----
    if (t < D) {
        const float of = rout[0][t] + rout[1][t] + rout[2][t] + rout[3][t];
        const long long fx = (long long)llrint((double)of * FIXS);
        __hip_atomic_fetch_add(&oacc[t], fx, __ATOMIC_RELAXED,
                               __HIP_MEMORY_SCOPE_AGENT);
    }
    if (t == 0) {
        const long long fa = (long long)llrint((double)ga_sh * FIXS);
        __hip_atomic_fetch_add(&oacc[D], fa, __ATOMIC_RELAXED,
                               __HIP_MEMORY_SCOPE_AGENT);
    }
    __syncthreads();

    // ---- ticket: last of 64 blocks divides and stores ----
    __shared__ int tick_sh;
    if (t == 0) {
        __threadfence();
        tick_sh = __hip_atomic_fetch_add(gcnt, 1, __ATOMIC_ACQ_REL,
                                         __HIP_MEMORY_SCOPE_AGENT);
    }
    __syncthreads();
    if (tick_sh != 63) return;

    __shared__ double asum_d;
    if (t == 0)
        asum_d = (double)__hip_atomic_load(&oacc[D], __ATOMIC_RELAXED,
                                           __HIP_MEMORY_SCOPE_AGENT);
    __syncthreads();
    if (t < D) {
        const long long num = __hip_atomic_load(&oacc[t], __ATOMIC_RELAXED,
                                                __HIP_MEMORY_SCOPE_AGENT);
        out[t] = (float)((double)num / asum_d);
    }
}

// ---------------------------------------------------------------------------
extern "C" void kernel_launch(void* const* d_in, const int* in_sizes, int n_in,
                              void* d_out, int out_size, void* d_ws, size_t ws_size,
                              hipStream_t stream) {
    const float* X       = (const float*)d_in[0];
    const float* W_sum   = (const float*)d_in[1];
    const float* W_alpha = (const float*)d_in[2];
    const float* b_alpha = (const float*)d_in[4];
    float* out = (float*)d_out;

    const int nrows = in_sizes[0] / D;   // 200000

    int NB = 2048;                       // multiple of 64
    auto need = [&](int nb) {
        return (size_t)nb * (D + 1) * sizeof(float)    // pw + pa
             + 256 + (D + 4) * sizeof(float)           // bw
             + 256 + (D + 1) * sizeof(long long)       // oacc
             + sizeof(int) + 64;                       // gcnt
    };
    while (NB > 64 && need(NB) > ws_size) NB >>= 1;

    char* ws = (char*)d_ws;
    float* pw = (float*)ws;
    float* pa = pw + (size_t)NB * D;
    size_t off = ((size_t)NB * (D + 1) * sizeof(float) + 255) & ~(size_t)255;
    float* bw = (float*)(ws + off);
    size_t off2 = (off + (D + 4) * sizeof(float) + 255) & ~(size_t)255;
    long long* oacc = (long long*)(ws + off2);
    int* gcnt = (int*)(oacc + (D + 1));

    prep_kernel<<<8, 256, 0, stream>>>(W_alpha, b_alpha, bw, oacc, gcnt);
    main_pass_kernel<<<NB, 256, 0, stream>>>(X, bw, pw, pa, nrows);
    r1mf_kernel<<<64, 512, 0, stream>>>(pw, pa, W_sum, oacc, gcnt, out, NB);
}